// Round 8
// baseline (476.527 us; speedup 1.0000x reference)
//
#include <hip/hip_runtime.h>
#include <math.h>

#define NJ 16
#define NV 778
#define M3 2334   // NV*3
#define S  8      // samples per block in k3a

typedef float f32x8  __attribute__((ext_vector_type(8)));
typedef float f32x16 __attribute__((ext_vector_type(16)));

__device__ __forceinline__ f32x8 splat8(float x) {
    f32x8 r = {x, x, x, x, x, x, x, x};
    return r;
}
// elementwise fused r = f*s + c  (all constant indices -> pure SSA)
__device__ __forceinline__ f32x8 fma8v(f32x8 f, float s, f32x8 c) {
    f32x8 r;
    r[0] = fmaf(f[0], s, c[0]); r[1] = fmaf(f[1], s, c[1]);
    r[2] = fmaf(f[2], s, c[2]); r[3] = fmaf(f[3], s, c[3]);
    r[4] = fmaf(f[4], s, c[4]); r[5] = fmaf(f[5], s, c[5]);
    r[6] = fmaf(f[6], s, c[6]); r[7] = fmaf(f[7], s, c[7]);
    return r;
}

// d_out layout (floats): verts [N*2334] | joints [N*48] | Rs [N*144]
// Stashes:
//   SJ/JT (528 floats) -> joints region (overwritten by k4 at the end)
//   A (N x 16 x 12)    -> d_ws (N*192 floats = 3.1 MB)
// Pipeline: k0 -> k1 -> k2(A->ws) -> k3a(v_posed->verts) -> k4(blend+joints fused)

// ---------------- K0: SJ[b,j,c] = sum_v shapedirs[b,v,c]*Jreg[v,j]; b==10 -> vtemp
__global__ __launch_bounds__(64) void k0_prep(
    const float* __restrict__ shapedirs,
    const float* __restrict__ Jreg,
    const float* __restrict__ vtemp,
    float* __restrict__ SJJT)   // 528 floats
{
    int b = blockIdx.x / 16;    // 0..9 = shapedirs row, 10 = vtemp
    int j = blockIdx.x % 16;
    int t = threadIdx.x;
    const float* src = (b < 10) ? (shapedirs + (size_t)b * M3) : vtemp;
    float a0 = 0.f, a1 = 0.f, a2 = 0.f;
    for (int v = t; v < NV; v += 64) {
        float jr = Jreg[v * 16 + j];
        a0 = fmaf(src[v*3 + 0], jr, a0);
        a1 = fmaf(src[v*3 + 1], jr, a1);
        a2 = fmaf(src[v*3 + 2], jr, a2);
    }
#pragma unroll
    for (int m = 1; m < 64; m <<= 1) {
        a0 += __shfl_xor(a0, m);
        a1 += __shfl_xor(a1, m);
        a2 += __shfl_xor(a2, m);
    }
    if (t == 0) {
        int base = (b < 10) ? (b*48 + j*3) : (480 + j*3);
        SJJT[base + 0] = a0;
        SJJT[base + 1] = a1;
        SJJT[base + 2] = a2;
    }
}

// ---------------- K1: Rodrigues, one thread per (n, joint)
__global__ __launch_bounds__(256) void k1_rodrigues(
    const float* __restrict__ theta, float* __restrict__ RsOut, int N)
{
    int idx = blockIdx.x * 256 + threadIdx.x;
    if (idx >= N * NJ) return;
    int n = idx >> 4;
    int j = idx & 15;
    float t0 = theta[n*48 + j*3 + 0];
    float t1 = theta[n*48 + j*3 + 1];
    float t2 = theta[n*48 + j*3 + 2];
    const float eps = 1e-8f;
    float a0 = t0 + eps, a1 = t1 + eps, a2 = t2 + eps;
    float angle = sqrtf(a0*a0 + a1*a1 + a2*a2);
    float inv  = 1.0f / angle;
    float half = 0.5f * angle;
    float sh = sinf(half), chh = cosf(half);
    float qw = chh;
    float qx = sh * t0 * inv;
    float qy = sh * t1 * inv;
    float qz = sh * t2 * inv;
    float qn = 1.0f / sqrtf(qw*qw + qx*qx + qy*qy + qz*qz);
    qw *= qn; qx *= qn; qy *= qn; qz *= qn;
    float w2=qw*qw, x2=qx*qx, y2=qy*qy, z2=qz*qz;
    float wx=qw*qx, wy=qw*qy, wz=qw*qz;
    float xy=qx*qy, xz=qx*qz, yz=qy*qz;
    float* R = RsOut + (size_t)idx * 9;
    R[0] = w2 + x2 - y2 - z2;
    R[1] = 2.f*(xy - wz);
    R[2] = 2.f*(wy + xz);
    R[3] = 2.f*(wz + xy);
    R[4] = w2 - x2 + y2 - z2;
    R[5] = 2.f*(yz - wx);
    R[6] = 2.f*(xz - wy);
    R[7] = 2.f*(wx + yz);
    R[8] = w2 - x2 - y2 + z2;
}

// ---------------- K2: kinematic chain -> A into d_ws (192 floats / sample)
__global__ __launch_bounds__(64) void k2_chain(
    const float* __restrict__ beta,
    const float* __restrict__ Rs,     // d_out Rs region
    const float* __restrict__ SJJT,   // 528 floats
    float* __restrict__ Aws,          // d_ws; A[n] at n*192
    int N)
{
    __shared__ float sS[528];
    for (int i = threadIdx.x; i < 528; i += 64) sS[i] = SJJT[i];
    __syncthreads();
    int gid = blockIdx.x * 64 + threadIdx.x;
    if (gid >= N * 5) return;
    int n  = gid / 5;
    int ch = gid % 5;

    float b[10];
#pragma unroll
    for (int i = 0; i < 10; ++i) b[i] = beta[n*10 + i];

    int jidx[4];
    jidx[0] = 0; jidx[1] = ch*3 + 1; jidx[2] = ch*3 + 2; jidx[3] = ch*3 + 3;
    float J[4][3];
#pragma unroll
    for (int q = 0; q < 4; ++q) {
        int j = jidx[q];
#pragma unroll
        for (int c = 0; c < 3; ++c) {
            float acc = sS[480 + j*3 + c];
#pragma unroll
            for (int qq = 0; qq < 10; ++qq)
                acc = fmaf(b[qq], sS[qq*48 + j*3 + c], acc);
            J[q][c] = acc;
        }
    }

    const float* Rn = Rs + (size_t)n * 144;
    float* An = Aws + (size_t)n * 192;

    float GpR[9], Gpt[3];
#pragma unroll
    for (int r = 0; r < 3; ++r) {
        GpR[r*3+0] =  Rn[r*3+0];
        GpR[r*3+1] = -Rn[r*3+1];
        GpR[r*3+2] = -Rn[r*3+2];
    }
    Gpt[0] = J[0][0]; Gpt[1] = J[0][1]; Gpt[2] = J[0][2];

    if (ch == 0) {
#pragma unroll
        for (int r = 0; r < 3; ++r) {
            float rel = GpR[r*3+0]*J[0][0] + GpR[r*3+1]*J[0][1] + GpR[r*3+2]*J[0][2];
            An[r*4 + 0] = GpR[r*3+0];
            An[r*4 + 1] = GpR[r*3+1];
            An[r*4 + 2] = GpR[r*3+2];
            An[r*4 + 3] = Gpt[r] - rel;
        }
    }

#pragma unroll
    for (int st = 0; st < 3; ++st) {
        int i = jidx[st+1];
        const float* Ri = Rn + (size_t)i * 9;
        float t0 = J[st+1][0] - J[st][0];
        float t1 = J[st+1][1] - J[st][1];
        float t2 = J[st+1][2] - J[st][2];
        float GR[9], Gt[3];
#pragma unroll
        for (int r = 0; r < 3; ++r) {
#pragma unroll
            for (int c = 0; c < 3; ++c)
                GR[r*3+c] = GpR[r*3+0]*Ri[c] + GpR[r*3+1]*Ri[3+c] + GpR[r*3+2]*Ri[6+c];
            Gt[r] = GpR[r*3+0]*t0 + GpR[r*3+1]*t1 + GpR[r*3+2]*t2 + Gpt[r];
        }
#pragma unroll
        for (int r = 0; r < 3; ++r) {
            float rel = GR[r*3+0]*J[st+1][0] + GR[r*3+1]*J[st+1][1] + GR[r*3+2]*J[st+1][2];
            An[i*12 + r*4 + 0] = GR[r*3+0];
            An[i*12 + r*4 + 1] = GR[r*3+1];
            An[i*12 + r*4 + 2] = GR[r*3+2];
            An[i*12 + r*4 + 3] = Gt[r] - rel;
        }
#pragma unroll
        for (int r = 0; r < 9; ++r) GpR[r] = GR[r];
        Gpt[0] = Gt[0]; Gpt[1] = Gt[1]; Gpt[2] = Gt[2];
    }
}

// ---------------- K3a: GEMM only. Block = 8 samples x 512-vert half; 256 thr x
// 2 vert-slots. acc = 6 f32x8 = 48 VGPR + temps ~= 75 total. (256,4) caps VGPR
// at 128 (ample) and guarantees 4 waves/EU; grid 1024 = 4 blocks/CU.
#define GSTEP(rowptr, fk) { \
    f32x8 fv_ = *(const f32x8*)&sF[(fk)][0]; \
    const float* r0_ = (rowptr) + 3*v0; \
    const float* r1_ = (rowptr) + 3*c1; \
    float x0_=r0_[0], y0_=r0_[1], z0_=r0_[2]; \
    float x1_=r1_[0], y1_=r1_[1], z1_=r1_[2]; \
    ax0=fma8v(fv_,x0_,ax0); ay0=fma8v(fv_,y0_,ay0); az0=fma8v(fv_,z0_,az0); \
    ax1=fma8v(fv_,x1_,ax1); ay1=fma8v(fv_,y1_,ay1); az1=fma8v(fv_,z1_,az1); }

#define STORE_SLOT(s_, ii, vv) if ((vv) < NV) { \
    float* o_ = vposed + (size_t)(n0 + s_)*M3 + (size_t)(vv)*3; \
    o_[0] = ax##ii[s_]; o_[1] = ay##ii[s_]; o_[2] = az##ii[s_]; }

#define STORE_S(s_) { STORE_SLOT(s_,0,v0) STORE_SLOT(s_,1,v1) }

__global__ __launch_bounds__(256, 4) void k3a_gemm(
    const float* __restrict__ beta,
    const float* __restrict__ posedirs,
    const float* __restrict__ shapedirs,
    const float* __restrict__ vtemp,
    const float* __restrict__ Rs,
    float* __restrict__ vposed,         // verts region
    int N)
{
    __shared__ __attribute__((aligned(32))) float sF[145][S]; // 10 beta + 135 posefeat
    const int n0   = blockIdx.x * S;
    const int half = blockIdx.y;
    const int tid  = threadIdx.x;

    // stage features: k<10 -> beta[k]; k>=10 -> Rs[9 + (k-10)] - I
    for (int idx = tid; idx < 145 * S; idx += 256) {
        int k = idx / S, s = idx % S;
        float val;
        if (k < 10) {
            val = beta[(size_t)(n0+s)*10 + k];
        } else {
            int kk = k - 10;
            int rr = kk % 9;
            val = Rs[(size_t)(n0+s)*144 + 9 + kk];
            if ((rr & 3) == 0) val -= 1.f;   // rr in {0,4,8}
        }
        sF[k][s] = val;
    }
    __syncthreads();

    const int v0 = half * 512 + tid;            // 0..767, always < 778
    const int v1 = v0 + 256;                    // may exceed NV when half==1
    const int c1 = (v1 < NV) ? v1 : (NV - 1);   // clamp: no divergent compute

    f32x8 ax0 = splat8(vtemp[v0*3+0]), ay0 = splat8(vtemp[v0*3+1]), az0 = splat8(vtemp[v0*3+2]);
    f32x8 ax1 = splat8(vtemp[c1*3+0]), ay1 = splat8(vtemp[c1*3+1]), az1 = splat8(vtemp[c1*3+2]);

    for (int k = 0; k < 10; ++k)  { GSTEP(shapedirs + (size_t)k*M3, k) }
    for (int k = 0; k < 135; ++k) { GSTEP(posedirs  + (size_t)k*M3, k + 10) }

    STORE_S(0) STORE_S(1) STORE_S(2) STORE_S(3)
    STORE_S(4) STORE_S(5) STORE_S(6) STORE_S(7)
}

// ---------------- K4: fused LBS blend + joint regression, butterfly-free.
// Phase 1: blend v_posed -> verts (global) + vbuf (LDS, c-major).
// Phase 2: 252 threads own (c, j-quad, vert-group-of-37): LDS read + float4
//          Jreg + 4 FMA per vertex. No shuffles at all.
// Phase 3: red[21][48] partials summed by 48 threads.
#define BJ(j_) { \
    float4 A0 = sA4[(j_)*3+0], A1 = sA4[(j_)*3+1], A2 = sA4[(j_)*3+2]; \
    float X_ = fmaf(A0.x,vx, fmaf(A0.y,vy, fmaf(A0.z,vz, A0.w))); \
    float Y_ = fmaf(A1.x,vx, fmaf(A1.y,vy, fmaf(A1.z,vz, A1.w))); \
    float Z_ = fmaf(A2.x,vx, fmaf(A2.y,vy, fmaf(A2.z,vz, A2.w))); \
    ox = fmaf(w[j_], X_, ox); \
    oy = fmaf(w[j_], Y_, oy); \
    oz = fmaf(w[j_], Z_, oz); }

__global__ __launch_bounds__(256, 4) void k4_blend_joints(
    const float* __restrict__ Aws,      // d_ws
    const float* __restrict__ weights,
    const float* __restrict__ Jreg,
    float* verts,                       // in-place: reads v_posed, writes verts
    float* __restrict__ joints,
    int N)
{
    __shared__ __attribute__((aligned(16))) float4 sA4[48];
    __shared__ float vbuf[3][NV];       // blended verts, c-major
    __shared__ float red[21][48];       // per-group joint partials
    const int n   = blockIdx.x;
    const int tid = threadIdx.x;
    if (tid < 48) sA4[tid] = reinterpret_cast<const float4*>(Aws + (size_t)n * 192)[tid];
    __syncthreads();

    // ---- Phase 1: blend (no joint accumulators held -> low VGPR)
    for (int v = tid; v < NV; v += 256) {
        float* vp = verts + (size_t)n * M3 + (size_t)v * 3;
        float vx = vp[0], vy = vp[1], vz = vp[2];
        f32x16 w = *reinterpret_cast<const f32x16*>(&weights[(size_t)v * 16]);
        float ox = 0.f, oy = 0.f, oz = 0.f;

        BJ(0)  BJ(1)  BJ(2)  BJ(3)  BJ(4)  BJ(5)  BJ(6)  BJ(7)
        BJ(8)  BJ(9)  BJ(10) BJ(11) BJ(12) BJ(13) BJ(14) BJ(15)

        vp[0] = ox; vp[1] = oy; vp[2] = oz;
        vbuf[0][v] = ox; vbuf[1][v] = oy; vbuf[2][v] = oz;
    }
    __syncthreads();

    // ---- Phase 2: output-parallel joint reduction (zero shuffles)
    if (tid < 252) {
        int c  = tid % 3;
        int jg = (tid / 3) & 3;          // j-quad: joints jg*4..jg*4+3
        int g  = tid / 12;               // vertex group 0..20
        int vbeg = g * 37;
        int vend = (g == 20) ? NV : vbeg + 37;
        float a0 = 0.f, a1 = 0.f, a2 = 0.f, a3 = 0.f;
        for (int v = vbeg; v < vend; ++v) {
            float x = vbuf[c][v];
            float4 jr = *reinterpret_cast<const float4*>(&Jreg[(size_t)v * 16 + jg * 4]);
            a0 = fmaf(jr.x, x, a0);
            a1 = fmaf(jr.y, x, a1);
            a2 = fmaf(jr.z, x, a2);
            a3 = fmaf(jr.w, x, a3);
        }
        red[g][(jg*4+0)*3 + c] = a0;
        red[g][(jg*4+1)*3 + c] = a1;
        red[g][(jg*4+2)*3 + c] = a2;
        red[g][(jg*4+3)*3 + c] = a3;
    }
    __syncthreads();

    // ---- Phase 3: final sum over 21 groups
    if (tid < 48) {
        float s = 0.f;
#pragma unroll
        for (int g = 0; g < 21; ++g) s += red[g][tid];
        joints[(size_t)n * 48 + tid] = s;
    }
}

extern "C" void kernel_launch(void* const* d_in, const int* in_sizes, int n_in,
                              void* d_out, int out_size, void* d_ws, size_t ws_size,
                              hipStream_t stream)
{
    const float* beta   = (const float*)d_in[0];
    const float* theta  = (const float*)d_in[1];
    const float* vtemp  = (const float*)d_in[2];
    const float* shaped = (const float*)d_in[3];
    const float* Jreg   = (const float*)d_in[4];
    const float* posed  = (const float*)d_in[5];
    const float* wts    = (const float*)d_in[6];
    float* out = (float*)d_out;
    const int N = in_sizes[0] / 10;   // 4096

    float* verts  = out;                            // N*2334
    float* joints = out + (size_t)N * M3;           // N*48
    float* RsOut  = joints + (size_t)N * 48;        // N*144
    float* Aws    = (float*)d_ws;                   // N*192 floats = 3.1 MB

    k0_prep<<<176, 64, 0, stream>>>(shaped, Jreg, vtemp, joints);
    k1_rodrigues<<<(N*NJ + 255)/256, 256, 0, stream>>>(theta, RsOut, N);
    k2_chain<<<(N*5 + 63)/64, 64, 0, stream>>>(beta, RsOut, joints, Aws, N);
    k3a_gemm<<<dim3(N/S, 2), 256, 0, stream>>>(beta, posed, shaped, vtemp, RsOut, verts, N);
    k4_blend_joints<<<N, 256, 0, stream>>>(Aws, wts, Jreg, verts, joints, N);
}

// Round 9
// 149.906 us; speedup vs baseline: 3.1788x; 3.1788x over previous
//
#include <hip/hip_runtime.h>
#include <math.h>

#define NJ 16
#define NV 778
#define M3 2334   // NV*3
#define S  8      // samples per block in k3a

typedef float f32x8  __attribute__((ext_vector_type(8)));
typedef float f32x16 __attribute__((ext_vector_type(16)));

__device__ __forceinline__ f32x8 splat8(float x) {
    f32x8 r = {x, x, x, x, x, x, x, x};
    return r;
}
// elementwise fused r = f*s + c  (all constant indices -> pure SSA)
__device__ __forceinline__ f32x8 fma8v(f32x8 f, float s, f32x8 c) {
    f32x8 r;
    r[0] = fmaf(f[0], s, c[0]); r[1] = fmaf(f[1], s, c[1]);
    r[2] = fmaf(f[2], s, c[2]); r[3] = fmaf(f[3], s, c[3]);
    r[4] = fmaf(f[4], s, c[4]); r[5] = fmaf(f[5], s, c[5]);
    r[6] = fmaf(f[6], s, c[6]); r[7] = fmaf(f[7], s, c[7]);
    return r;
}

// d_out layout (floats): verts [N*2334] | joints [N*48] | Rs [N*144]
// Stashes:
//   SJ/JT (528 floats) -> joints region (overwritten by k4 at the end)
//   A (N x 16 x 12)    -> d_ws (N*192 floats = 3.1 MB)
// Pipeline: k0 -> k1 -> k2(A->ws) -> k3a(v_posed->verts) -> k4(blend+joints fused)
//
// LAUNCH-BOUNDS LESSON (R4, R8): second arg w empirically caps VGPR at
// 512/(2w) on this toolchain (arg=4 -> 64-VGPR cap -> catastrophic spill).
// Only (B, 1) is trustworthy (cap ~256). Control occupancy via actual
// register usage + grid, never via the second arg.

// ---------------- K0: SJ[b,j,c] = sum_v shapedirs[b,v,c]*Jreg[v,j]; b==10 -> vtemp
__global__ __launch_bounds__(64) void k0_prep(
    const float* __restrict__ shapedirs,
    const float* __restrict__ Jreg,
    const float* __restrict__ vtemp,
    float* __restrict__ SJJT)   // 528 floats
{
    int b = blockIdx.x / 16;    // 0..9 = shapedirs row, 10 = vtemp
    int j = blockIdx.x % 16;
    int t = threadIdx.x;
    const float* src = (b < 10) ? (shapedirs + (size_t)b * M3) : vtemp;
    float a0 = 0.f, a1 = 0.f, a2 = 0.f;
    for (int v = t; v < NV; v += 64) {
        float jr = Jreg[v * 16 + j];
        a0 = fmaf(src[v*3 + 0], jr, a0);
        a1 = fmaf(src[v*3 + 1], jr, a1);
        a2 = fmaf(src[v*3 + 2], jr, a2);
    }
#pragma unroll
    for (int m = 1; m < 64; m <<= 1) {
        a0 += __shfl_xor(a0, m);
        a1 += __shfl_xor(a1, m);
        a2 += __shfl_xor(a2, m);
    }
    if (t == 0) {
        int base = (b < 10) ? (b*48 + j*3) : (480 + j*3);
        SJJT[base + 0] = a0;
        SJJT[base + 1] = a1;
        SJJT[base + 2] = a2;
    }
}

// ---------------- K1: Rodrigues, one thread per (n, joint)
__global__ __launch_bounds__(256) void k1_rodrigues(
    const float* __restrict__ theta, float* __restrict__ RsOut, int N)
{
    int idx = blockIdx.x * 256 + threadIdx.x;
    if (idx >= N * NJ) return;
    int n = idx >> 4;
    int j = idx & 15;
    float t0 = theta[n*48 + j*3 + 0];
    float t1 = theta[n*48 + j*3 + 1];
    float t2 = theta[n*48 + j*3 + 2];
    const float eps = 1e-8f;
    float a0 = t0 + eps, a1 = t1 + eps, a2 = t2 + eps;
    float angle = sqrtf(a0*a0 + a1*a1 + a2*a2);
    float inv  = 1.0f / angle;
    float half = 0.5f * angle;
    float sh = sinf(half), chh = cosf(half);
    float qw = chh;
    float qx = sh * t0 * inv;
    float qy = sh * t1 * inv;
    float qz = sh * t2 * inv;
    float qn = 1.0f / sqrtf(qw*qw + qx*qx + qy*qy + qz*qz);
    qw *= qn; qx *= qn; qy *= qn; qz *= qn;
    float w2=qw*qw, x2=qx*qx, y2=qy*qy, z2=qz*qz;
    float wx=qw*qx, wy=qw*qy, wz=qw*qz;
    float xy=qx*qy, xz=qx*qz, yz=qy*qz;
    float* R = RsOut + (size_t)idx * 9;
    R[0] = w2 + x2 - y2 - z2;
    R[1] = 2.f*(xy - wz);
    R[2] = 2.f*(wy + xz);
    R[3] = 2.f*(wz + xy);
    R[4] = w2 - x2 + y2 - z2;
    R[5] = 2.f*(yz - wx);
    R[6] = 2.f*(xz - wy);
    R[7] = 2.f*(wx + yz);
    R[8] = w2 - x2 - y2 + z2;
}

// ---------------- K2: kinematic chain -> A into d_ws (192 floats / sample)
__global__ __launch_bounds__(64) void k2_chain(
    const float* __restrict__ beta,
    const float* __restrict__ Rs,     // d_out Rs region
    const float* __restrict__ SJJT,   // 528 floats
    float* __restrict__ Aws,          // d_ws; A[n] at n*192
    int N)
{
    __shared__ float sS[528];
    for (int i = threadIdx.x; i < 528; i += 64) sS[i] = SJJT[i];
    __syncthreads();
    int gid = blockIdx.x * 64 + threadIdx.x;
    if (gid >= N * 5) return;
    int n  = gid / 5;
    int ch = gid % 5;

    float b[10];
#pragma unroll
    for (int i = 0; i < 10; ++i) b[i] = beta[n*10 + i];

    int jidx[4];
    jidx[0] = 0; jidx[1] = ch*3 + 1; jidx[2] = ch*3 + 2; jidx[3] = ch*3 + 3;
    float J[4][3];
#pragma unroll
    for (int q = 0; q < 4; ++q) {
        int j = jidx[q];
#pragma unroll
        for (int c = 0; c < 3; ++c) {
            float acc = sS[480 + j*3 + c];
#pragma unroll
            for (int qq = 0; qq < 10; ++qq)
                acc = fmaf(b[qq], sS[qq*48 + j*3 + c], acc);
            J[q][c] = acc;
        }
    }

    const float* Rn = Rs + (size_t)n * 144;
    float* An = Aws + (size_t)n * 192;

    float GpR[9], Gpt[3];
#pragma unroll
    for (int r = 0; r < 3; ++r) {
        GpR[r*3+0] =  Rn[r*3+0];
        GpR[r*3+1] = -Rn[r*3+1];
        GpR[r*3+2] = -Rn[r*3+2];
    }
    Gpt[0] = J[0][0]; Gpt[1] = J[0][1]; Gpt[2] = J[0][2];

    if (ch == 0) {
#pragma unroll
        for (int r = 0; r < 3; ++r) {
            float rel = GpR[r*3+0]*J[0][0] + GpR[r*3+1]*J[0][1] + GpR[r*3+2]*J[0][2];
            An[r*4 + 0] = GpR[r*3+0];
            An[r*4 + 1] = GpR[r*3+1];
            An[r*4 + 2] = GpR[r*3+2];
            An[r*4 + 3] = Gpt[r] - rel;
        }
    }

#pragma unroll
    for (int st = 0; st < 3; ++st) {
        int i = jidx[st+1];
        const float* Ri = Rn + (size_t)i * 9;
        float t0 = J[st+1][0] - J[st][0];
        float t1 = J[st+1][1] - J[st][1];
        float t2 = J[st+1][2] - J[st][2];
        float GR[9], Gt[3];
#pragma unroll
        for (int r = 0; r < 3; ++r) {
#pragma unroll
            for (int c = 0; c < 3; ++c)
                GR[r*3+c] = GpR[r*3+0]*Ri[c] + GpR[r*3+1]*Ri[3+c] + GpR[r*3+2]*Ri[6+c];
            Gt[r] = GpR[r*3+0]*t0 + GpR[r*3+1]*t1 + GpR[r*3+2]*t2 + Gpt[r];
        }
#pragma unroll
        for (int r = 0; r < 3; ++r) {
            float rel = GR[r*3+0]*J[st+1][0] + GR[r*3+1]*J[st+1][1] + GR[r*3+2]*J[st+1][2];
            An[i*12 + r*4 + 0] = GR[r*3+0];
            An[i*12 + r*4 + 1] = GR[r*3+1];
            An[i*12 + r*4 + 2] = GR[r*3+2];
            An[i*12 + r*4 + 3] = Gt[r] - rel;
        }
#pragma unroll
        for (int r = 0; r < 9; ++r) GpR[r] = GR[r];
        Gpt[0] = Gt[0]; Gpt[1] = Gt[1]; Gpt[2] = Gt[2];
    }
}

// ---------------- K3a: GEMM only. Block = 8 samples x 512-vert half; 256 thr x
// 2 vert-slots. acc = 6 f32x8 = 48 VGPR + temps ~= 90 total. (256,1): cap ~256,
// no spill; grid 1024 = 4 blocks/CU = 16 waves/CU (VGPR-feasible at ~90).
#define GSTEP(rowptr, fk) { \
    f32x8 fv_ = *(const f32x8*)&sF[(fk)][0]; \
    const float* r0_ = (rowptr) + 3*v0; \
    const float* r1_ = (rowptr) + 3*c1; \
    float x0_=r0_[0], y0_=r0_[1], z0_=r0_[2]; \
    float x1_=r1_[0], y1_=r1_[1], z1_=r1_[2]; \
    ax0=fma8v(fv_,x0_,ax0); ay0=fma8v(fv_,y0_,ay0); az0=fma8v(fv_,z0_,az0); \
    ax1=fma8v(fv_,x1_,ax1); ay1=fma8v(fv_,y1_,ay1); az1=fma8v(fv_,z1_,az1); }

#define STORE_SLOT(s_, ii, vv) if ((vv) < NV) { \
    float* o_ = vposed + (size_t)(n0 + s_)*M3 + (size_t)(vv)*3; \
    o_[0] = ax##ii[s_]; o_[1] = ay##ii[s_]; o_[2] = az##ii[s_]; }

#define STORE_S(s_) { STORE_SLOT(s_,0,v0) STORE_SLOT(s_,1,v1) }

__global__ __launch_bounds__(256, 1) void k3a_gemm(
    const float* __restrict__ beta,
    const float* __restrict__ posedirs,
    const float* __restrict__ shapedirs,
    const float* __restrict__ vtemp,
    const float* __restrict__ Rs,
    float* __restrict__ vposed,         // verts region
    int N)
{
    __shared__ __attribute__((aligned(32))) float sF[145][S]; // 10 beta + 135 posefeat
    const int n0   = blockIdx.x * S;
    const int half = blockIdx.y;
    const int tid  = threadIdx.x;

    // stage features: k<10 -> beta[k]; k>=10 -> Rs[9 + (k-10)] - I
    for (int idx = tid; idx < 145 * S; idx += 256) {
        int k = idx / S, s = idx % S;
        float val;
        if (k < 10) {
            val = beta[(size_t)(n0+s)*10 + k];
        } else {
            int kk = k - 10;
            int rr = kk % 9;
            val = Rs[(size_t)(n0+s)*144 + 9 + kk];
            if ((rr & 3) == 0) val -= 1.f;   // rr in {0,4,8}
        }
        sF[k][s] = val;
    }
    __syncthreads();

    const int v0 = half * 512 + tid;            // 0..767, always < 778
    const int v1 = v0 + 256;                    // may exceed NV when half==1
    const int c1 = (v1 < NV) ? v1 : (NV - 1);   // clamp: no divergent compute

    f32x8 ax0 = splat8(vtemp[v0*3+0]), ay0 = splat8(vtemp[v0*3+1]), az0 = splat8(vtemp[v0*3+2]);
    f32x8 ax1 = splat8(vtemp[c1*3+0]), ay1 = splat8(vtemp[c1*3+1]), az1 = splat8(vtemp[c1*3+2]);

    for (int k = 0; k < 10; ++k)  { GSTEP(shapedirs + (size_t)k*M3, k) }
    for (int k = 0; k < 135; ++k) { GSTEP(posedirs  + (size_t)k*M3, k + 10) }

    STORE_S(0) STORE_S(1) STORE_S(2) STORE_S(3)
    STORE_S(4) STORE_S(5) STORE_S(6) STORE_S(7)
}

// ---------------- K4: fused LBS blend + joint regression, butterfly-free.
// Phase 1: blend v_posed -> verts (global) + vbuf (LDS, c-major).
// Phase 2: 252 threads own (c, j-quad, vert-group-of-37): LDS read + float4
//          Jreg + 4 FMA per vertex. No shuffles at all.
// Phase 3: red[21][48] partials summed by 48 threads.
#define BJ(j_) { \
    float4 A0 = sA4[(j_)*3+0], A1 = sA4[(j_)*3+1], A2 = sA4[(j_)*3+2]; \
    float X_ = fmaf(A0.x,vx, fmaf(A0.y,vy, fmaf(A0.z,vz, A0.w))); \
    float Y_ = fmaf(A1.x,vx, fmaf(A1.y,vy, fmaf(A1.z,vz, A1.w))); \
    float Z_ = fmaf(A2.x,vx, fmaf(A2.y,vy, fmaf(A2.z,vz, A2.w))); \
    ox = fmaf(w[j_], X_, ox); \
    oy = fmaf(w[j_], Y_, oy); \
    oz = fmaf(w[j_], Z_, oz); }

__global__ __launch_bounds__(256, 1) void k4_blend_joints(
    const float* __restrict__ Aws,      // d_ws
    const float* __restrict__ weights,
    const float* __restrict__ Jreg,
    float* verts,                       // in-place: reads v_posed, writes verts
    float* __restrict__ joints,
    int N)
{
    __shared__ __attribute__((aligned(16))) float4 sA4[48];
    __shared__ float vbuf[3][NV];       // blended verts, c-major
    __shared__ float red[21][48];       // per-group joint partials
    const int n   = blockIdx.x;
    const int tid = threadIdx.x;
    if (tid < 48) sA4[tid] = reinterpret_cast<const float4*>(Aws + (size_t)n * 192)[tid];
    __syncthreads();

    // ---- Phase 1: blend (no joint accumulators held -> low VGPR)
    for (int v = tid; v < NV; v += 256) {
        float* vp = verts + (size_t)n * M3 + (size_t)v * 3;
        float vx = vp[0], vy = vp[1], vz = vp[2];
        f32x16 w = *reinterpret_cast<const f32x16*>(&weights[(size_t)v * 16]);
        float ox = 0.f, oy = 0.f, oz = 0.f;

        BJ(0)  BJ(1)  BJ(2)  BJ(3)  BJ(4)  BJ(5)  BJ(6)  BJ(7)
        BJ(8)  BJ(9)  BJ(10) BJ(11) BJ(12) BJ(13) BJ(14) BJ(15)

        vp[0] = ox; vp[1] = oy; vp[2] = oz;
        vbuf[0][v] = ox; vbuf[1][v] = oy; vbuf[2][v] = oz;
    }
    __syncthreads();

    // ---- Phase 2: output-parallel joint reduction (zero shuffles)
    if (tid < 252) {
        int c  = tid % 3;
        int jg = (tid / 3) & 3;          // j-quad: joints jg*4..jg*4+3
        int g  = tid / 12;               // vertex group 0..20
        int vbeg = g * 37;
        int vend = (g == 20) ? NV : vbeg + 37;
        float a0 = 0.f, a1 = 0.f, a2 = 0.f, a3 = 0.f;
        for (int v = vbeg; v < vend; ++v) {
            float x = vbuf[c][v];
            float4 jr = *reinterpret_cast<const float4*>(&Jreg[(size_t)v * 16 + jg * 4]);
            a0 = fmaf(jr.x, x, a0);
            a1 = fmaf(jr.y, x, a1);
            a2 = fmaf(jr.z, x, a2);
            a3 = fmaf(jr.w, x, a3);
        }
        red[g][(jg*4+0)*3 + c] = a0;
        red[g][(jg*4+1)*3 + c] = a1;
        red[g][(jg*4+2)*3 + c] = a2;
        red[g][(jg*4+3)*3 + c] = a3;
    }
    __syncthreads();

    // ---- Phase 3: final sum over 21 groups
    if (tid < 48) {
        float s = 0.f;
#pragma unroll
        for (int g = 0; g < 21; ++g) s += red[g][tid];
        joints[(size_t)n * 48 + tid] = s;
    }
}

extern "C" void kernel_launch(void* const* d_in, const int* in_sizes, int n_in,
                              void* d_out, int out_size, void* d_ws, size_t ws_size,
                              hipStream_t stream)
{
    const float* beta   = (const float*)d_in[0];
    const float* theta  = (const float*)d_in[1];
    const float* vtemp  = (const float*)d_in[2];
    const float* shaped = (const float*)d_in[3];
    const float* Jreg   = (const float*)d_in[4];
    const float* posed  = (const float*)d_in[5];
    const float* wts    = (const float*)d_in[6];
    float* out = (float*)d_out;
    const int N = in_sizes[0] / 10;   // 4096

    float* verts  = out;                            // N*2334
    float* joints = out + (size_t)N * M3;           // N*48
    float* RsOut  = joints + (size_t)N * 48;        // N*144
    float* Aws    = (float*)d_ws;                   // N*192 floats = 3.1 MB

    k0_prep<<<176, 64, 0, stream>>>(shaped, Jreg, vtemp, joints);
    k1_rodrigues<<<(N*NJ + 255)/256, 256, 0, stream>>>(theta, RsOut, N);
    k2_chain<<<(N*5 + 63)/64, 64, 0, stream>>>(beta, RsOut, joints, Aws, N);
    k3a_gemm<<<dim3(N/S, 2), 256, 0, stream>>>(beta, posed, shaped, vtemp, RsOut, verts, N);
    k4_blend_joints<<<N, 256, 0, stream>>>(Aws, wts, Jreg, verts, joints, N);
}